// Round 1
// baseline (1026.304 us; speedup 1.0000x reference)
//
#include <hip/hip_runtime.h>
#include <hip/hip_bf16.h>
#include <cstdint>
#include <cstddef>

#define B_ 16
#define T_ 2048
#define C_ 1024
#define H_ 256

typedef __attribute__((ext_vector_type(8))) short short8;
typedef __attribute__((ext_vector_type(4))) float f32x4;

// fp32 -> bf16 (RNE), bit-level (matches numpy-style rounding)
__device__ inline unsigned short f2bf(float f) {
    unsigned int u = __builtin_bit_cast(unsigned int, f);
    unsigned int r = (u + 0x7FFFu + ((u >> 16) & 1u)) >> 16;
    return (unsigned short)r;
}

// ---------------------------------------------------------------------------
// Kernel 1: W [K=1024][N=256] fp32  ->  Wt [mat][N][K] bf16  (B^T layout)
// ---------------------------------------------------------------------------
__global__ void wconv(const float* __restrict__ Wq, const float* __restrict__ Wk,
                      const float* __restrict__ Wv, unsigned short* __restrict__ Wt) {
    int idx = blockIdx.x * 256 + threadIdx.x;
    const int per = C_ * H_;             // 262144
    if (idx >= 3 * per) return;
    int mat = idx / per;
    int rem = idx - mat * per;
    int n = rem / C_;                    // output-major => coalesced writes
    int k = rem - n * C_;
    const float* W = (mat == 0) ? Wq : (mat == 1) ? Wk : Wv;
    Wt[idx] = f2bf(W[(size_t)k * H_ + n]);
}

// ---------------------------------------------------------------------------
// Kernel 2: QKV projection GEMM.  [32768 x 1024] @ [1024 x 256] per mat.
// Block = 256 thr (4 waves); each block does 64 rows x all 256 cols of 1 mat.
// Each wave: 16 rows x 256 cols via 16 n-tiles of 16x16x32 MFMA.
// Q,K stored [B*T][H] bf16; V stored transposed [B][H][T] bf16.
// ---------------------------------------------------------------------------
__global__ __launch_bounds__(256) void qkv_gemm(
    const float* __restrict__ x, const unsigned short* __restrict__ Wt,
    const float* __restrict__ bq, const float* __restrict__ bk,
    const float* __restrict__ bv,
    unsigned short* __restrict__ Qb, unsigned short* __restrict__ Kb,
    unsigned short* __restrict__ Vt)
{
    const int mat = blockIdx.y;
    const int wid  = threadIdx.x >> 6;
    const int lane = threadIdx.x & 63;
    const int c16  = lane & 15;
    const int g    = lane >> 4;
    const int r0   = blockIdx.x * 64 + wid * 16;

    const float* xp = x + (size_t)(r0 + c16) * C_ + g * 8;
    const unsigned short* wp = Wt + (size_t)mat * H_ * C_ + (size_t)c16 * C_ + g * 8;

    f32x4 acc[16];
#pragma unroll
    for (int i = 0; i < 16; ++i) acc[i] = f32x4{0.f, 0.f, 0.f, 0.f};

    for (int ks = 0; ks < C_ / 32; ++ks) {
        f32x4 a0 = *(const f32x4*)(xp + ks * 32);
        f32x4 a1 = *(const f32x4*)(xp + ks * 32 + 4);
        short8 af;
        af[0] = (short)f2bf(a0[0]); af[1] = (short)f2bf(a0[1]);
        af[2] = (short)f2bf(a0[2]); af[3] = (short)f2bf(a0[3]);
        af[4] = (short)f2bf(a1[0]); af[5] = (short)f2bf(a1[1]);
        af[6] = (short)f2bf(a1[2]); af[7] = (short)f2bf(a1[3]);
#pragma unroll
        for (int nt = 0; nt < 16; ++nt) {
            short8 bfr = *(const short8*)(wp + (size_t)nt * 16 * C_ + ks * 32);
            acc[nt] = __builtin_amdgcn_mfma_f32_16x16x32_bf16(af, bfr, acc[nt], 0, 0, 0);
        }
    }

    const float* bias = (mat == 0) ? bq : (mat == 1) ? bk : bv;
#pragma unroll
    for (int nt = 0; nt < 16; ++nt) {
        const int n = nt * 16 + c16;
        const float bias_v = bias[n];
#pragma unroll
        for (int r = 0; r < 4; ++r) {
            const int rr = r0 + g * 4 + r;
            const unsigned short hv = f2bf(acc[nt][r] + bias_v);
            if (mat == 0)      Qb[(size_t)rr * H_ + n] = hv;
            else if (mat == 1) Kb[(size_t)rr * H_ + n] = hv;
            else {
                const int bb = rr >> 11, tt = rr & (T_ - 1);
                Vt[((size_t)bb * H_ + n) * T_ + tt] = hv;
            }
        }
    }
}

// ---------------------------------------------------------------------------
// Kernel 3: flash attention. Block = 64 q-rows (4 waves x 16), KV tile = 64.
// S = mfma(Q, K^T) in C-layout; online softmax (row spread over 16 lanes,
// shfl_xor reduce); P -> bf16 -> XOR-swizzled per-wave LDS -> A-frag for PV.
// ---------------------------------------------------------------------------
__global__ __launch_bounds__(256) void attn(
    const unsigned short* __restrict__ Qb, const unsigned short* __restrict__ Kb,
    const unsigned short* __restrict__ Vt, float* __restrict__ out)
{
    const int b   = blockIdx.y;
    const int q0  = blockIdx.x * 64;
    const int wid  = threadIdx.x >> 6;
    const int lane = threadIdx.x & 63;
    const int c16  = lane & 15;
    const int g    = lane >> 4;
    const int qw   = q0 + wid * 16;

    __shared__ unsigned short Plds[4][16 * 64];

    // Q fragments (hoisted): 16 rows x 256 head dims per wave
    short8 qf[8];
    const unsigned short* qp = Qb + (size_t)(b * T_ + qw + c16) * H_ + g * 8;
#pragma unroll
    for (int kc = 0; kc < 8; ++kc) qf[kc] = *(const short8*)(qp + kc * 32);

    f32x4 o[16];
#pragma unroll
    for (int i = 0; i < 16; ++i) o[i] = f32x4{0.f, 0.f, 0.f, 0.f};
    float m[4], ll[4];
#pragma unroll
    for (int r = 0; r < 4; ++r) { m[r] = -1e30f; ll[r] = 0.f; }

    const float inv_scale = 0.022097086912079608f;   // 1/sqrt(2048)
    const unsigned short* kb = Kb + (size_t)b * T_ * H_;
    const unsigned short* vb = Vt + (size_t)b * H_ * T_;

    for (int s = 0; s <= q0; s += 64) {
        const bool diag = (s == q0);

        // ---- S = Q K^T over the 64-wide kv tile (4 col-tiles of 16) ----
        f32x4 sc4[4];
#pragma unroll
        for (int ct = 0; ct < 4; ++ct) {
            f32x4 sa = f32x4{0.f, 0.f, 0.f, 0.f};
            const unsigned short* kp = kb + (size_t)(s + ct * 16 + c16) * H_ + g * 8;
#pragma unroll
            for (int kc = 0; kc < 8; ++kc) {
                short8 kf = *(const short8*)(kp + kc * 32);
                sa = __builtin_amdgcn_mfma_f32_16x16x32_bf16(qf[kc], kf, sa, 0, 0, 0);
            }
            sc4[ct] = sa;
        }

        // ---- online softmax ----
        float scf[4];
#pragma unroll
        for (int r = 0; r < 4; ++r) {
            const int qrow = qw + g * 4 + r;
#pragma unroll
            for (int ct = 0; ct < 4; ++ct) {
                float v = sc4[ct][r] * inv_scale;
                if (diag && (s + ct * 16 + c16) > qrow) v = -1e30f;
                sc4[ct][r] = v;
            }
            float mx = fmaxf(fmaxf(sc4[0][r], sc4[1][r]), fmaxf(sc4[2][r], sc4[3][r]));
#pragma unroll
            for (int msk = 1; msk < 16; msk <<= 1) mx = fmaxf(mx, __shfl_xor(mx, msk, 64));
            const float nm = fmaxf(m[r], mx);
            scf[r] = __expf(m[r] - nm);
            m[r] = nm;
            float rsum = 0.f;
#pragma unroll
            for (int ct = 0; ct < 4; ++ct) {
                const float p = __expf(sc4[ct][r] - nm);
                sc4[ct][r] = p;
                rsum += p;
            }
#pragma unroll
            for (int msk = 1; msk < 16; msk <<= 1) rsum += __shfl_xor(rsum, msk, 64);
            ll[r] = ll[r] * scf[r] + rsum;
        }
#pragma unroll
        for (int nt = 0; nt < 16; ++nt) {
            o[nt][0] *= scf[0]; o[nt][1] *= scf[1];
            o[nt][2] *= scf[2]; o[nt][3] *= scf[3];
        }

        // ---- P (C-layout f32) -> bf16 -> swizzled LDS ----
#pragma unroll
        for (int r = 0; r < 4; ++r) {
            const int row = g * 4 + r;
#pragma unroll
            for (int ct = 0; ct < 4; ++ct) {
                const int col = ct * 16 + c16;
                Plds[wid][row * 64 + (col ^ ((row & 7) << 3))] = f2bf(sc4[ct][r]);
            }
        }
        __syncthreads();   // intra-wave LDS ordering; all waves share trip count

        // ---- re-load P as A-fragments ----
        short8 pa[2];
#pragma unroll
        for (int kk = 0; kk < 2; ++kk) {
            const int idx = c16 * 64 + ((kk * 32 + g * 8) ^ ((c16 & 7) << 3));
            pa[kk] = *(const short8*)&Plds[wid][idx];
        }

        // ---- O += P V  (V transposed: [H][T], contiguous in kv) ----
#pragma unroll
        for (int nt = 0; nt < 16; ++nt) {
            const unsigned short* vp = vb + (size_t)(nt * 16 + c16) * T_ + s + g * 8;
            short8 v0 = *(const short8*)vp;
            short8 v1 = *(const short8*)(vp + 32);
            o[nt] = __builtin_amdgcn_mfma_f32_16x16x32_bf16(pa[0], v0, o[nt], 0, 0, 0);
            o[nt] = __builtin_amdgcn_mfma_f32_16x16x32_bf16(pa[1], v1, o[nt], 0, 0, 0);
        }
    }

    // ---- epilogue: out = O / l ----
    float* op = out + (size_t)(b * T_ + qw) * H_;
    float inv[4];
#pragma unroll
    for (int r = 0; r < 4; ++r) inv[r] = 1.f / ll[r];
#pragma unroll
    for (int nt = 0; nt < 16; ++nt) {
#pragma unroll
        for (int r = 0; r < 4; ++r) {
            op[(size_t)(g * 4 + r) * H_ + nt * 16 + c16] = o[nt][r] * inv[r];
        }
    }
}

// ---------------------------------------------------------------------------
extern "C" void kernel_launch(void* const* d_in, const int* in_sizes, int n_in,
                              void* d_out, int out_size, void* d_ws, size_t ws_size,
                              hipStream_t stream) {
    const float* x  = (const float*)d_in[0];
    const float* Wq = (const float*)d_in[1];
    const float* bq = (const float*)d_in[2];
    const float* Wk = (const float*)d_in[3];
    const float* bk = (const float*)d_in[4];
    const float* Wv = (const float*)d_in[5];
    const float* bv = (const float*)d_in[6];
    float* out = (float*)d_out;

    char* ws = (char*)d_ws;
    unsigned short* Wt = (unsigned short*)ws;                    // 1.5 MiB
    unsigned short* Qb = (unsigned short*)(ws + (2u  << 20));    // 16 MiB
    unsigned short* Kb = (unsigned short*)(ws + (18u << 20));    // 16 MiB
    unsigned short* Vt = (unsigned short*)(ws + (34u << 20));    // 16 MiB  (total 50 MiB)

    hipLaunchKernelGGL(wconv, dim3((3 * C_ * H_ + 255) / 256), dim3(256), 0, stream,
                       Wq, Wk, Wv, Wt);
    hipLaunchKernelGGL(qkv_gemm, dim3(T_ * B_ / 64, 3), dim3(256), 0, stream,
                       x, Wt, bq, bk, bv, Qb, Kb, Vt);
    hipLaunchKernelGGL(attn, dim3(T_ / 64, B_), dim3(256), 0, stream,
                       Qb, Kb, Vt, out);
}

// Round 2
// 453.058 us; speedup vs baseline: 2.2653x; 2.2653x over previous
//
#include <hip/hip_runtime.h>
#include <hip/hip_bf16.h>
#include <cstdint>
#include <cstddef>

#define B_ 16
#define T_ 2048
#define C_ 1024
#define H_ 256
#define KVB 32

typedef __attribute__((ext_vector_type(8))) short short8;
typedef __attribute__((ext_vector_type(4))) float f32x4;

// fp32 -> bf16 (RNE)
__device__ inline unsigned short f2bf(float f) {
    unsigned int u = __builtin_bit_cast(unsigned int, f);
    unsigned int r = (u + 0x7FFFu + ((u >> 16) & 1u)) >> 16;
    return (unsigned short)r;
}

// async global->LDS, 16B per lane; lds ptr must be wave-uniform base
__device__ inline void glds16(const void* g, void* l) {
    __builtin_amdgcn_global_load_lds(
        (const __attribute__((address_space(1))) unsigned int*)g,
        (__attribute__((address_space(3))) unsigned int*)l, 16, 0, 0);
}

// ---------------------------------------------------------------------------
// Kernel 1: W [K=1024][N=256] fp32 -> Wt [mat][N][K] bf16  (B^T layout)
// ---------------------------------------------------------------------------
__global__ void wconv(const float* __restrict__ Wq, const float* __restrict__ Wk,
                      const float* __restrict__ Wv, unsigned short* __restrict__ Wt) {
    int idx = blockIdx.x * 256 + threadIdx.x;
    const int per = C_ * H_;
    if (idx >= 3 * per) return;
    int mat = idx / per;
    int rem = idx - mat * per;
    int n = rem / C_;
    int k = rem - n * C_;
    const float* W = (mat == 0) ? Wq : (mat == 1) ? Wk : Wv;
    Wt[idx] = f2bf(W[(size_t)k * H_ + n]);
}

// ---------------------------------------------------------------------------
// Kernel 2: QKV GEMM. Block = 512 thr (8 waves) x 128 rows, mat = blockIdx.y.
// W chunk [256n][64k] staged to LDS via swizzled global_load_lds, dbuf.
// ---------------------------------------------------------------------------
__global__ __launch_bounds__(512) void qkv_gemm(
    const float* __restrict__ x, const unsigned short* __restrict__ Wt,
    const float* __restrict__ bq, const float* __restrict__ bk,
    const float* __restrict__ bv,
    unsigned short* __restrict__ Qb, unsigned short* __restrict__ Kb,
    unsigned short* __restrict__ Vt)
{
    const int mat = blockIdx.y;
    const int tid = threadIdx.x;
    const int wid = tid >> 6;
    const int lane = tid & 63;
    const int c16 = lane & 15;
    const int g = lane >> 4;
    const int rw = blockIdx.x * 128 + wid * 16;

    __shared__ __align__(16) unsigned short Wl[2][256 * 64];   // 2 x 32KB, swizzled

    const char* wbB = (const char*)(Wt + (size_t)mat * H_ * C_);   // [n][k] bf16
    const float* xp = x + (size_t)(rw + c16) * C_ + g * 8;

    f32x4 acc[16];
#pragma unroll
    for (int i = 0; i < 16; ++i) acc[i] = f32x4{0.f, 0.f, 0.f, 0.f};

    // stage chunk 0 + prefetch x chunk 0
#pragma unroll
    for (int j = 0; j < 4; ++j) {
        int off = j * 8192 + wid * 1024 + lane * 16;
        int row = off >> 7, colb = off & 127;
        glds16(wbB + (size_t)row * 2048 + (colb ^ ((row & 7) << 4)),
               (char*)&Wl[0][0] + j * 8192 + wid * 1024);
    }
    f32x4 xr[4];
    xr[0] = *(const f32x4*)(xp);      xr[1] = *(const f32x4*)(xp + 4);
    xr[2] = *(const f32x4*)(xp + 32); xr[3] = *(const f32x4*)(xp + 36);
    __syncthreads();

    for (int ch = 0; ch < 16; ++ch) {
        const int cur = ch & 1;
        short8 af[2];
#pragma unroll
        for (int kk = 0; kk < 2; ++kk)
#pragma unroll
            for (int e = 0; e < 4; ++e) {
                af[kk][e]     = (short)f2bf(xr[kk * 2][e]);
                af[kk][e + 4] = (short)f2bf(xr[kk * 2 + 1][e]);
            }
        if (ch < 15) {
            const float* p = xp + (ch + 1) * 64;
            xr[0] = *(const f32x4*)(p);      xr[1] = *(const f32x4*)(p + 4);
            xr[2] = *(const f32x4*)(p + 32); xr[3] = *(const f32x4*)(p + 36);
#pragma unroll
            for (int j = 0; j < 4; ++j) {
                int off = j * 8192 + wid * 1024 + lane * 16;
                int row = off >> 7, colb = off & 127;
                glds16(wbB + (size_t)row * 2048 + (ch + 1) * 128 + (colb ^ ((row & 7) << 4)),
                       (char*)&Wl[cur ^ 1][0] + j * 8192 + wid * 1024);
            }
        }
#pragma unroll
        for (int kk = 0; kk < 2; ++kk)
#pragma unroll
            for (int nt = 0; nt < 16; ++nt) {
                int n = nt * 16 + c16;
                short8 bfr = *(const short8*)((const char*)&Wl[cur][0] + n * 128 +
                                              ((kk * 64 + g * 16) ^ ((n & 7) << 4)));
                acc[nt] = __builtin_amdgcn_mfma_f32_16x16x32_bf16(af[kk], bfr, acc[nt], 0, 0, 0);
            }
        __syncthreads();   // drains glds (vmcnt) + guards dbuf swap
    }

    const float* bias = (mat == 0) ? bq : (mat == 1) ? bk : bv;
#pragma unroll
    for (int nt = 0; nt < 16; ++nt) {
        const int n = nt * 16 + c16;
        const float bias_v = bias[n];
#pragma unroll
        for (int r = 0; r < 4; ++r) {
            const int rr = rw + g * 4 + r;
            const unsigned short hv = f2bf(acc[nt][r] + bias_v);
            if (mat == 0)      Qb[(size_t)rr * H_ + n] = hv;
            else if (mat == 1) Kb[(size_t)rr * H_ + n] = hv;
            else {
                const int bb = rr >> 11, tt = rr & (T_ - 1);
                Vt[((size_t)bb * H_ + n) * T_ + tt] = hv;
            }
        }
    }
}

// ---------------------------------------------------------------------------
// Kernel 3: flash attention. Block = 64 q-rows (4 waves x 16), KV tile = 32.
// K: global_load_lds dbuf, source-pre-swizzled. V^T: reg-staged into padded
// slot-swizzled LDS (T14 split). P wave-local via lgkmcnt fence.
// ---------------------------------------------------------------------------
__global__ __launch_bounds__(256) void attn(
    const unsigned short* __restrict__ Qb, const unsigned short* __restrict__ Kb,
    const unsigned short* __restrict__ Vt, float* __restrict__ out)
{
    const int b = blockIdx.y;
    const int bx = blockIdx.x;
    const int qi = (bx & 1) ? (31 - (bx >> 1)) : (bx >> 1);   // long/short interleave
    const int q0 = qi * 64;
    const int tid = threadIdx.x;
    const int wid = tid >> 6;
    const int lane = tid & 63;
    const int c16 = lane & 15;
    const int g = lane >> 4;
    const int qw = q0 + wid * 16;

    __shared__ __align__(16) unsigned short Kl[2][KVB * 256];   // 2 x 16KB, swizzled
    __shared__ __align__(16) unsigned short Vl[256 * 40];       // 20KB, pad+slot swz
    __shared__ __align__(16) unsigned short Pl[4][16 * 32];     // 4KB, wave-local

    const char* kbB = (const char*)(Kb + (size_t)b * T_ * H_);
    const unsigned short* vb = Vt + (size_t)b * H_ * T_;

    // hoist Q fragments: 16 rows x 256 dims per wave
    short8 qf[8];
    const unsigned short* qp = Qb + (size_t)(b * T_ + qw + c16) * H_ + g * 8;
#pragma unroll
    for (int kc = 0; kc < 8; ++kc) qf[kc] = *(const short8*)(qp + kc * 32);

    f32x4 o[16];
#pragma unroll
    for (int i = 0; i < 16; ++i) o[i] = f32x4{0.f, 0.f, 0.f, 0.f};
    float m[4], ll[4];
#pragma unroll
    for (int r = 0; r < 4; ++r) { m[r] = -1e30f; ll[r] = 0.f; }

    const float inv_scale = 0.022097086912079608f;   // 1/sqrt(2048)
    const int ntiles = q0 / KVB + 2;
    const int vsl = (tid >> 3) & 3;                  // V write slot swizzle
    short8 vreg[4];

    // ---- prologue: stage tile 0 ----
#pragma unroll
    for (int j = 0; j < 4; ++j) {
        int off = j * 4096 + wid * 1024 + lane * 16;
        int row = off >> 9, colb = off & 511;
        glds16(kbB + (size_t)row * 512 + (colb ^ ((row & 7) << 4)),
               (char*)&Kl[0][0] + j * 4096 + wid * 1024);
    }
    {
        const unsigned short* p = vb + (size_t)tid * T_;
#pragma unroll
        for (int c = 0; c < 4; ++c) vreg[c] = *(const short8*)(p + c * 8);
    }
    __syncthreads();   // drains vmcnt: K0 in LDS, vreg loaded
#pragma unroll
    for (int c = 0; c < 4; ++c)
        *(short8*)(&Vl[tid * 40 + ((c ^ vsl) * 8)]) = vreg[c];
    __syncthreads();   // V0 visible

    for (int t = 0; t < ntiles; ++t) {
        const int cur = t & 1;
        const int s = t * KVB;
        const bool have_next = (t + 1 < ntiles);

        if (have_next) {
#pragma unroll
            for (int j = 0; j < 4; ++j) {
                int off = j * 4096 + wid * 1024 + lane * 16;
                int row = off >> 9, colb = off & 511;
                glds16(kbB + (size_t)(t + 1) * KVB * 512 + (size_t)row * 512 +
                           (colb ^ ((row & 7) << 4)),
                       (char*)&Kl[cur ^ 1][0] + j * 4096 + wid * 1024);
            }
            const unsigned short* p = vb + (size_t)tid * T_ + (t + 1) * KVB;
#pragma unroll
            for (int c = 0; c < 4; ++c) vreg[c] = *(const short8*)(p + c * 8);
        }

        if (s <= qw + 15) {   // wave-uniform: skip fully-masked tiles
            // ---- S = Q K^T ----
            f32x4 sc[2];
#pragma unroll
            for (int ct = 0; ct < 2; ++ct) {
                f32x4 sa = f32x4{0.f, 0.f, 0.f, 0.f};
                const int row = ct * 16 + c16;
#pragma unroll
                for (int kc = 0; kc < 8; ++kc) {
                    short8 kf = *(const short8*)((const char*)&Kl[cur][0] + row * 512 +
                                                 ((kc * 64 + g * 16) ^ ((row & 7) << 4)));
                    sa = __builtin_amdgcn_mfma_f32_16x16x32_bf16(qf[kc], kf, sa, 0, 0, 0);
                }
                sc[ct] = sa;
            }

            // ---- online softmax ----
            const bool needm = (s + KVB > qw);
            float scf[4];
#pragma unroll
            for (int r = 0; r < 4; ++r) {
                const int qrow = qw + g * 4 + r;
#pragma unroll
                for (int ct = 0; ct < 2; ++ct) {
                    float v = sc[ct][r] * inv_scale;
                    if (needm && (s + ct * 16 + c16) > qrow) v = -1e30f;
                    sc[ct][r] = v;
                }
                float mx = fmaxf(sc[0][r], sc[1][r]);
#pragma unroll
                for (int msk = 1; msk < 16; msk <<= 1) mx = fmaxf(mx, __shfl_xor(mx, msk, 64));
                const float nm = fmaxf(m[r], mx);
                scf[r] = __expf(m[r] - nm);
                m[r] = nm;
                float rsum = 0.f;
#pragma unroll
                for (int ct = 0; ct < 2; ++ct) {
                    const float p = __expf(sc[ct][r] - nm);
                    sc[ct][r] = p;
                    rsum += p;
                }
#pragma unroll
                for (int msk = 1; msk < 16; msk <<= 1) rsum += __shfl_xor(rsum, msk, 64);
                ll[r] = ll[r] * scf[r] + rsum;
            }
            if (__any(scf[0] < 1.f || scf[1] < 1.f || scf[2] < 1.f || scf[3] < 1.f)) {
#pragma unroll
                for (int nt = 0; nt < 16; ++nt) {
                    o[nt][0] *= scf[0]; o[nt][1] *= scf[1];
                    o[nt][2] *= scf[2]; o[nt][3] *= scf[3];
                }
            }

            // ---- P -> bf16 -> wave-local swizzled LDS ----
#pragma unroll
            for (int r = 0; r < 4; ++r) {
                const int row = g * 4 + r;
#pragma unroll
                for (int ct = 0; ct < 2; ++ct) {
                    const int col = ct * 16 + c16;
                    Pl[wid][row * 32 + (((col >> 3) ^ g) & 3) * 8 + (col & 7)] =
                        f2bf(sc[ct][r]);
                }
            }
            asm volatile("s_waitcnt lgkmcnt(0)" ::: "memory");
            __builtin_amdgcn_sched_barrier(0);
            short8 pa = *(const short8*)((const char*)&Pl[wid][0] + c16 * 64 +
                                         (((g ^ (c16 >> 2)) & 3) << 4));

            // ---- O += P V ----
#pragma unroll
            for (int nt = 0; nt < 16; ++nt) {
                const int n = nt * 16 + c16;
                short8 vf = *(const short8*)((const char*)Vl + n * 80 +
                                             (((g ^ ((n >> 3) & 3)) & 3) << 4));
                o[nt] = __builtin_amdgcn_mfma_f32_16x16x32_bf16(pa, vf, o[nt], 0, 0, 0);
            }
        }

        __syncthreads();   // all waves done reading Vl/K[cur]; drains next-tile glds
        if (have_next) {
#pragma unroll
            for (int c = 0; c < 4; ++c)
                *(short8*)(&Vl[tid * 40 + ((c ^ vsl) * 8)]) = vreg[c];
        }
        __syncthreads();   // V(t+1) + K(t+1) visible
    }

    // ---- epilogue ----
    float* op = out + (size_t)(b * T_ + qw) * H_;
    float inv[4];
#pragma unroll
    for (int r = 0; r < 4; ++r) inv[r] = 1.f / ll[r];
#pragma unroll
    for (int nt = 0; nt < 16; ++nt) {
#pragma unroll
        for (int r = 0; r < 4; ++r) {
            op[(size_t)(g * 4 + r) * H_ + nt * 16 + c16] = o[nt][r] * inv[r];
        }
    }
}

// ---------------------------------------------------------------------------
extern "C" void kernel_launch(void* const* d_in, const int* in_sizes, int n_in,
                              void* d_out, int out_size, void* d_ws, size_t ws_size,
                              hipStream_t stream) {
    const float* x  = (const float*)d_in[0];
    const float* Wq = (const float*)d_in[1];
    const float* bq = (const float*)d_in[2];
    const float* Wk = (const float*)d_in[3];
    const float* bk = (const float*)d_in[4];
    const float* Wv = (const float*)d_in[5];
    const float* bv = (const float*)d_in[6];
    float* out = (float*)d_out;

    char* ws = (char*)d_ws;
    unsigned short* Wt = (unsigned short*)ws;                    // 1.5 MiB
    unsigned short* Qb = (unsigned short*)(ws + (2u  << 20));    // 16 MiB
    unsigned short* Kb = (unsigned short*)(ws + (18u << 20));    // 16 MiB
    unsigned short* Vt = (unsigned short*)(ws + (34u << 20));    // 16 MiB

    hipLaunchKernelGGL(wconv, dim3((3 * C_ * H_ + 255) / 256), dim3(256), 0, stream,
                       Wq, Wk, Wv, Wt);
    hipLaunchKernelGGL(qkv_gemm, dim3(T_ * B_ / 128, 3), dim3(512), 0, stream,
                       x, Wt, bq, bk, bv, Qb, Kb, Vt);
    hipLaunchKernelGGL(attn, dim3(T_ / 64, B_), dim3(256), 0, stream,
                       Qb, Kb, Vt, out);
}

// Round 3
// 426.580 us; speedup vs baseline: 2.4059x; 1.0621x over previous
//
#include <hip/hip_runtime.h>
#include <hip/hip_bf16.h>
#include <cstdint>
#include <cstddef>

#define B_ 16
#define T_ 2048
#define C_ 1024
#define H_ 256
#define KVB 32

typedef __attribute__((ext_vector_type(8))) short short8;
typedef __attribute__((ext_vector_type(4))) float f32x4;

// fp32 -> bf16 (RNE)
__device__ inline unsigned short f2bf(float f) {
    unsigned int u = __builtin_bit_cast(unsigned int, f);
    unsigned int r = (u + 0x7FFFu + ((u >> 16) & 1u)) >> 16;
    return (unsigned short)r;
}

// async global->LDS, 16B/lane; LDS dest is wave-uniform base (+lane*16 by HW)
__device__ inline void glds16(const void* g, void* l) {
    __builtin_amdgcn_global_load_lds(
        (const __attribute__((address_space(1))) unsigned int*)g,
        (__attribute__((address_space(3))) unsigned int*)l, 16, 0, 0);
}

// ---------------------------------------------------------------------------
// Kernel 0: x [B*T][C] fp32 -> xb bf16 (vectorized, grid-stride)
// ---------------------------------------------------------------------------
__global__ __launch_bounds__(256) void xconv(const float* __restrict__ x,
                                             unsigned short* __restrict__ xb) {
    const int stride = gridDim.x * 256;
    const int n8 = B_ * T_ * C_ / 8;
    for (int i = blockIdx.x * 256 + threadIdx.x; i < n8; i += stride) {
        f32x4 v0 = *(const f32x4*)(x + (size_t)i * 8);
        f32x4 v1 = *(const f32x4*)(x + (size_t)i * 8 + 4);
        short8 o;
#pragma unroll
        for (int e = 0; e < 4; ++e) {
            o[e] = (short)f2bf(v0[e]);
            o[e + 4] = (short)f2bf(v1[e]);
        }
        *(short8*)(xb + (size_t)i * 8) = o;
    }
}

// ---------------------------------------------------------------------------
// Kernel 1: W [K=1024][N=256] fp32 -> Wt [mat][N][K] bf16  (B^T layout)
// ---------------------------------------------------------------------------
__global__ void wconv(const float* __restrict__ Wq, const float* __restrict__ Wk,
                      const float* __restrict__ Wv, unsigned short* __restrict__ Wt) {
    int idx = blockIdx.x * 256 + threadIdx.x;
    const int per = C_ * H_;
    if (idx >= 3 * per) return;
    int mat = idx / per;
    int rem = idx - mat * per;
    int n = rem / C_;
    int k = rem - n * C_;
    const float* W = (mat == 0) ? Wq : (mat == 1) ? Wk : Wv;
    Wt[idx] = f2bf(W[(size_t)k * H_ + n]);
}

// ---------------------------------------------------------------------------
// Kernel 2: QKV GEMM (bf16 A). Block = 512 thr (8 waves) x 128 rows.
// W chunk [256n][64k] staged to LDS via swizzled global_load_lds, dbuf.
// ---------------------------------------------------------------------------
__global__ __launch_bounds__(512) void qkv_gemm(
    const unsigned short* __restrict__ xb, const unsigned short* __restrict__ Wt,
    const float* __restrict__ bq, const float* __restrict__ bk,
    const float* __restrict__ bv,
    unsigned short* __restrict__ Qb, unsigned short* __restrict__ Kb,
    unsigned short* __restrict__ Vt)
{
    const int mat = blockIdx.y;
    const int tid = threadIdx.x;
    const int wid = tid >> 6;
    const int lane = tid & 63;
    const int c16 = lane & 15;
    const int g = lane >> 4;
    const int rw = blockIdx.x * 128 + wid * 16;

    __shared__ __align__(16) unsigned short Wl[2][256 * 64];   // 2 x 32KB, swizzled

    const char* wbB = (const char*)(Wt + (size_t)mat * H_ * C_);   // [n][k] bf16
    const unsigned short* xp = xb + (size_t)(rw + c16) * C_ + g * 8;

    f32x4 acc[16];
#pragma unroll
    for (int i = 0; i < 16; ++i) acc[i] = f32x4{0.f, 0.f, 0.f, 0.f};

#pragma unroll
    for (int j = 0; j < 4; ++j) {
        int off = j * 8192 + wid * 1024 + lane * 16;
        int row = off >> 7, colb = off & 127;
        glds16(wbB + (size_t)row * 2048 + (colb ^ ((row & 7) << 4)),
               (char*)&Wl[0][0] + j * 8192 + wid * 1024);
    }
    short8 xr[2];
    xr[0] = *(const short8*)(xp);
    xr[1] = *(const short8*)(xp + 32);
    __syncthreads();

    for (int ch = 0; ch < 16; ++ch) {
        const int cur = ch & 1;
        short8 af[2] = {xr[0], xr[1]};
        if (ch < 15) {
            xr[0] = *(const short8*)(xp + (ch + 1) * 64);
            xr[1] = *(const short8*)(xp + (ch + 1) * 64 + 32);
#pragma unroll
            for (int j = 0; j < 4; ++j) {
                int off = j * 8192 + wid * 1024 + lane * 16;
                int row = off >> 7, colb = off & 127;
                glds16(wbB + (size_t)row * 2048 + (ch + 1) * 128 + (colb ^ ((row & 7) << 4)),
                       (char*)&Wl[cur ^ 1][0] + j * 8192 + wid * 1024);
            }
        }
#pragma unroll
        for (int kk = 0; kk < 2; ++kk)
#pragma unroll
            for (int nt = 0; nt < 16; ++nt) {
                int n = nt * 16 + c16;
                short8 bfr = *(const short8*)((const char*)&Wl[cur][0] + n * 128 +
                                              ((kk * 64 + g * 16) ^ ((n & 7) << 4)));
                acc[nt] = __builtin_amdgcn_mfma_f32_16x16x32_bf16(af[kk], bfr, acc[nt], 0, 0, 0);
            }
        __syncthreads();   // drains glds (vmcnt) + guards dbuf swap
    }

    const float* bias = (mat == 0) ? bq : (mat == 1) ? bk : bv;
#pragma unroll
    for (int nt = 0; nt < 16; ++nt) {
        const int n = nt * 16 + c16;
        const float bias_v = bias[n];
#pragma unroll
        for (int r = 0; r < 4; ++r) {
            const int rr = rw + g * 4 + r;
            const unsigned short hv = f2bf(acc[nt][r] + bias_v);
            if (mat == 0)      Qb[(size_t)rr * H_ + n] = hv;
            else if (mat == 1) Kb[(size_t)rr * H_ + n] = hv;
            else {
                const int bb = rr >> 11, tt = rr & (T_ - 1);
                Vt[((size_t)bb * H_ + n) * T_ + tt] = hv;
            }
        }
    }
}

// ---------------------------------------------------------------------------
// Kernel 3: flash attention. Block = 32 q-rows (2 waves x 16), KV tile = 32.
// Grid 64x16 (2x backfill at 2 blocks/CU). XCD-balanced qi mapping.
// K and V^T both staged via glds (dbuf); one barrier per tile.
// V LDS layout [4 kv-grp][256 n][8 kv] -> conflict-free b128 reads.
// ---------------------------------------------------------------------------
__global__ __launch_bounds__(128) void attn(
    const unsigned short* __restrict__ Qb, const unsigned short* __restrict__ Kb,
    const unsigned short* __restrict__ Vt, float* __restrict__ out)
{
    const int b = blockIdx.y;
    const int bx = blockIdx.x;                 // 0..63
    const int cc = bx & 7, jj = bx >> 3;
    const int qi = (jj < 4) ? (cc + 8 * jj) : (63 - cc - 8 * (jj - 4));
    const int q0 = qi * 32;
    const int ntiles = qi + 1;
    const int tid = threadIdx.x;
    const int wid = tid >> 6;                  // 0..1
    const int lane = tid & 63;
    const int c16 = lane & 15;
    const int g = lane >> 4;
    const int qw = q0 + wid * 16;

    __shared__ __align__(16) unsigned short Kl[2][KVB * 256];     // 2 x 16KB swz
    __shared__ __align__(16) unsigned short Vl[2][4 * 256 * 8];   // 2 x 16KB subtiled
    __shared__ __align__(16) unsigned short Pl[2][16 * 32];       // 1KB/wave

    const char* kbB = (const char*)(Kb + (size_t)b * T_ * H_);
    const unsigned short* vb = Vt + (size_t)b * H_ * T_;

    // hoist Q fragments: 16 rows x 256 dims per wave
    short8 qf[8];
    const unsigned short* qp = Qb + (size_t)(b * T_ + qw + c16) * H_ + g * 8;
#pragma unroll
    for (int kc = 0; kc < 8; ++kc) qf[kc] = *(const short8*)(qp + kc * 32);

    f32x4 o[16];
#pragma unroll
    for (int i = 0; i < 16; ++i) o[i] = f32x4{0.f, 0.f, 0.f, 0.f};
    float m[4], ll[4];
#pragma unroll
    for (int r = 0; r < 4; ++r) { m[r] = -1e30f; ll[r] = 0.f; }

    const float inv_scale = 0.022097086912079608f;   // 1/sqrt(2048)

    // ---- prologue: stage tile 0 ----
#pragma unroll
    for (int j = 0; j < 8; ++j) {
        int off = wid * 8192 + j * 1024 + lane * 16;
        int row = off >> 9, colb = off & 511;
        glds16(kbB + (size_t)row * 512 + (colb ^ ((row & 7) << 4)),
               (char*)&Kl[0][0] + wid * 8192 + j * 1024);
    }
#pragma unroll
    for (int j = 0; j < 8; ++j) {
        int off = wid * 8192 + j * 1024 + lane * 16;
        int g4 = off >> 12, n = (off >> 4) & 255;
        glds16((const char*)(vb + (size_t)n * T_ + g4 * 8),
               (char*)&Vl[0][0] + wid * 8192 + j * 1024);
    }
    __syncthreads();

    for (int t = 0; t < ntiles; ++t) {
        const int cur = t & 1;
        const int s = t * KVB;

        if (t + 1 < ntiles) {
            const int sn = s + KVB;
#pragma unroll
            for (int j = 0; j < 8; ++j) {
                int off = wid * 8192 + j * 1024 + lane * 16;
                int row = off >> 9, colb = off & 511;
                glds16(kbB + (size_t)(sn + row) * 512 + (colb ^ ((row & 7) << 4)),
                       (char*)&Kl[cur ^ 1][0] + wid * 8192 + j * 1024);
            }
#pragma unroll
            for (int j = 0; j < 8; ++j) {
                int off = wid * 8192 + j * 1024 + lane * 16;
                int g4 = off >> 12, n = (off >> 4) & 255;
                glds16((const char*)(vb + (size_t)n * T_ + sn + g4 * 8),
                       (char*)&Vl[cur ^ 1][0] + wid * 8192 + j * 1024);
            }
        }

        // ---- S = Q K^T ----
        f32x4 sc[2];
#pragma unroll
        for (int ct = 0; ct < 2; ++ct) {
            f32x4 sa = f32x4{0.f, 0.f, 0.f, 0.f};
            const int row = ct * 16 + c16;
#pragma unroll
            for (int kc = 0; kc < 8; ++kc) {
                short8 kf = *(const short8*)((const char*)&Kl[cur][0] + row * 512 +
                                             ((kc * 64 + g * 16) ^ ((row & 7) << 4)));
                sa = __builtin_amdgcn_mfma_f32_16x16x32_bf16(qf[kc], kf, sa, 0, 0, 0);
            }
            sc[ct] = sa;
        }

        // ---- online softmax ----
        const bool needm = (t == ntiles - 1);
        float scf[4];
#pragma unroll
        for (int r = 0; r < 4; ++r) {
            const int qrow = qw + g * 4 + r;
#pragma unroll
            for (int ct = 0; ct < 2; ++ct) {
                float v = sc[ct][r] * inv_scale;
                if (needm && (s + ct * 16 + c16) > qrow) v = -1e30f;
                sc[ct][r] = v;
            }
            float mx = fmaxf(sc[0][r], sc[1][r]);
#pragma unroll
            for (int msk = 1; msk < 16; msk <<= 1) mx = fmaxf(mx, __shfl_xor(mx, msk, 64));
            const float nm = fmaxf(m[r], mx);
            scf[r] = __expf(m[r] - nm);
            m[r] = nm;
            float rsum = 0.f;
#pragma unroll
            for (int ct = 0; ct < 2; ++ct) {
                const float p = __expf(sc[ct][r] - nm);
                sc[ct][r] = p;
                rsum += p;
            }
#pragma unroll
            for (int msk = 1; msk < 16; msk <<= 1) rsum += __shfl_xor(rsum, msk, 64);
            ll[r] = ll[r] * scf[r] + rsum;
        }
        if (__any(scf[0] < 1.f || scf[1] < 1.f || scf[2] < 1.f || scf[3] < 1.f)) {
#pragma unroll
            for (int nt = 0; nt < 16; ++nt) {
                o[nt][0] *= scf[0]; o[nt][1] *= scf[1];
                o[nt][2] *= scf[2]; o[nt][3] *= scf[3];
            }
        }

        // ---- P -> bf16 -> wave-local swizzled LDS ----
#pragma unroll
        for (int r = 0; r < 4; ++r) {
            const int row = g * 4 + r;
#pragma unroll
            for (int ct = 0; ct < 2; ++ct) {
                const int col = ct * 16 + c16;
                const int slot = ((col >> 3) ^ g) & 3;
                Pl[wid][row * 32 + slot * 8 + (col & 7)] = f2bf(sc[ct][r]);
            }
        }
        asm volatile("s_waitcnt lgkmcnt(0)" ::: "memory");
        __builtin_amdgcn_sched_barrier(0);
        short8 pa = *(const short8*)((const char*)&Pl[wid][0] + c16 * 64 +
                                     (((g ^ (c16 >> 2)) & 3) << 4));

        // ---- O += P V ----
#pragma unroll
        for (int nt = 0; nt < 16; ++nt) {
            const int n = nt * 16 + c16;
            short8 vf = *(const short8*)((const char*)&Vl[cur][0] + ((g * 256 + n) << 4));
            o[nt] = __builtin_amdgcn_mfma_f32_16x16x32_bf16(pa, vf, o[nt], 0, 0, 0);
        }

        __syncthreads();   // drains next-tile glds; guards dbuf + Pl reuse
    }

    // ---- epilogue ----
    float* op = out + (size_t)(b * T_ + qw) * H_;
    float inv[4];
#pragma unroll
    for (int r = 0; r < 4; ++r) inv[r] = 1.f / ll[r];
#pragma unroll
    for (int nt = 0; nt < 16; ++nt) {
#pragma unroll
        for (int r = 0; r < 4; ++r) {
            op[(size_t)(g * 4 + r) * H_ + nt * 16 + c16] = o[nt][r] * inv[r];
        }
    }
}

// ---------------------------------------------------------------------------
extern "C" void kernel_launch(void* const* d_in, const int* in_sizes, int n_in,
                              void* d_out, int out_size, void* d_ws, size_t ws_size,
                              hipStream_t stream) {
    const float* x  = (const float*)d_in[0];
    const float* Wq = (const float*)d_in[1];
    const float* bq = (const float*)d_in[2];
    const float* Wk = (const float*)d_in[3];
    const float* bk = (const float*)d_in[4];
    const float* Wv = (const float*)d_in[5];
    const float* bv = (const float*)d_in[6];
    float* out = (float*)d_out;

    char* ws = (char*)d_ws;
    unsigned short* Wt = (unsigned short*)ws;                    // 1.5 MiB
    unsigned short* Qb = (unsigned short*)(ws + (2u  << 20));    // 16 MiB
    unsigned short* Kb = (unsigned short*)(ws + (18u << 20));    // 16 MiB
    unsigned short* Vt = (unsigned short*)(ws + (34u << 20));    // 16 MiB
    unsigned short* xb = (unsigned short*)(ws + (50u << 20));    // 64 MiB (total 114)

    hipLaunchKernelGGL(xconv, dim3(2048), dim3(256), 0, stream, x, xb);
    hipLaunchKernelGGL(wconv, dim3((3 * C_ * H_ + 255) / 256), dim3(256), 0, stream,
                       Wq, Wk, Wv, Wt);
    hipLaunchKernelGGL(qkv_gemm, dim3(T_ * B_ / 128, 3), dim3(512), 0, stream,
                       xb, Wt, bq, bk, bv, Qb, Kb, Vt);
    hipLaunchKernelGGL(attn, dim3(64, B_), dim3(128), 0, stream,
                       Qb, Kb, Vt, out);
}

// Round 4
// 256.908 us; speedup vs baseline: 3.9948x; 1.6604x over previous
//
#include <hip/hip_runtime.h>
#include <hip/hip_bf16.h>
#include <cstdint>
#include <cstddef>

#define B_ 16
#define T_ 2048
#define C_ 1024
#define H_ 256
#define KVB 32

typedef __attribute__((ext_vector_type(8))) short short8;
typedef __attribute__((ext_vector_type(4))) float f32x4;

// fp32 -> bf16 (RNE)
__device__ inline unsigned short f2bf(float f) {
    unsigned int u = __builtin_bit_cast(unsigned int, f);
    unsigned int r = (u + 0x7FFFu + ((u >> 16) & 1u)) >> 16;
    return (unsigned short)r;
}

// async global->LDS, 16B/lane; LDS dest wave-uniform base (+lane*16 by HW)
__device__ inline void glds16(const void* g, void* l) {
    __builtin_amdgcn_global_load_lds(
        (const __attribute__((address_space(1))) unsigned int*)g,
        (__attribute__((address_space(3))) unsigned int*)l, 16, 0, 0);
}

// ---------------------------------------------------------------------------
// Kernel 0: x fp32 -> bf16
// ---------------------------------------------------------------------------
__global__ __launch_bounds__(256) void xconv(const float* __restrict__ x,
                                             unsigned short* __restrict__ xb) {
    const int stride = gridDim.x * 256;
    const int n8 = B_ * T_ * C_ / 8;
    for (int i = blockIdx.x * 256 + threadIdx.x; i < n8; i += stride) {
        f32x4 v0 = *(const f32x4*)(x + (size_t)i * 8);
        f32x4 v1 = *(const f32x4*)(x + (size_t)i * 8 + 4);
        short8 o;
#pragma unroll
        for (int e = 0; e < 4; ++e) {
            o[e] = (short)f2bf(v0[e]);
            o[e + 4] = (short)f2bf(v1[e]);
        }
        *(short8*)(xb + (size_t)i * 8) = o;
    }
}

// ---------------------------------------------------------------------------
// Kernel 1: W [K][N] fp32 -> Wt [mat][N][K] bf16
// ---------------------------------------------------------------------------
__global__ void wconv(const float* __restrict__ Wq, const float* __restrict__ Wk,
                      const float* __restrict__ Wv, unsigned short* __restrict__ Wt) {
    int idx = blockIdx.x * 256 + threadIdx.x;
    const int per = C_ * H_;
    if (idx >= 3 * per) return;
    int mat = idx / per;
    int rem = idx - mat * per;
    int n = rem / C_;
    int k = rem - n * C_;
    const float* W = (mat == 0) ? Wq : (mat == 1) ? Wk : Wv;
    Wt[idx] = f2bf(W[(size_t)k * H_ + n]);
}

// ---------------------------------------------------------------------------
// Kernel 2: QKV GEMM (unchanged from R3)
// ---------------------------------------------------------------------------
__global__ __launch_bounds__(512) void qkv_gemm(
    const unsigned short* __restrict__ xb, const unsigned short* __restrict__ Wt,
    const float* __restrict__ bq, const float* __restrict__ bk,
    const float* __restrict__ bv,
    unsigned short* __restrict__ Qb, unsigned short* __restrict__ Kb,
    unsigned short* __restrict__ Vt)
{
    const int mat = blockIdx.y;
    const int tid = threadIdx.x;
    const int wid = tid >> 6;
    const int lane = tid & 63;
    const int c16 = lane & 15;
    const int g = lane >> 4;
    const int rw = blockIdx.x * 128 + wid * 16;

    __shared__ __align__(16) unsigned short Wl[2][256 * 64];

    const char* wbB = (const char*)(Wt + (size_t)mat * H_ * C_);
    const unsigned short* xp = xb + (size_t)(rw + c16) * C_ + g * 8;

    f32x4 acc[16];
#pragma unroll
    for (int i = 0; i < 16; ++i) acc[i] = f32x4{0.f, 0.f, 0.f, 0.f};

#pragma unroll
    for (int j = 0; j < 4; ++j) {
        int off = j * 8192 + wid * 1024 + lane * 16;
        int row = off >> 7, colb = off & 127;
        glds16(wbB + (size_t)row * 2048 + (colb ^ ((row & 7) << 4)),
               (char*)&Wl[0][0] + j * 8192 + wid * 1024);
    }
    short8 xr[2];
    xr[0] = *(const short8*)(xp);
    xr[1] = *(const short8*)(xp + 32);
    __syncthreads();

    for (int ch = 0; ch < 16; ++ch) {
        const int cur = ch & 1;
        short8 af[2] = {xr[0], xr[1]};
        if (ch < 15) {
            xr[0] = *(const short8*)(xp + (ch + 1) * 64);
            xr[1] = *(const short8*)(xp + (ch + 1) * 64 + 32);
#pragma unroll
            for (int j = 0; j < 4; ++j) {
                int off = j * 8192 + wid * 1024 + lane * 16;
                int row = off >> 7, colb = off & 127;
                glds16(wbB + (size_t)row * 2048 + (ch + 1) * 128 + (colb ^ ((row & 7) << 4)),
                       (char*)&Wl[cur ^ 1][0] + j * 8192 + wid * 1024);
            }
        }
#pragma unroll
        for (int kk = 0; kk < 2; ++kk)
#pragma unroll
            for (int nt = 0; nt < 16; ++nt) {
                int n = nt * 16 + c16;
                short8 bfr = *(const short8*)((const char*)&Wl[cur][0] + n * 128 +
                                              ((kk * 64 + g * 16) ^ ((n & 7) << 4)));
                acc[nt] = __builtin_amdgcn_mfma_f32_16x16x32_bf16(af[kk], bfr, acc[nt], 0, 0, 0);
            }
        __syncthreads();
    }

    const float* bias = (mat == 0) ? bq : (mat == 1) ? bk : bv;
#pragma unroll
    for (int nt = 0; nt < 16; ++nt) {
        const int n = nt * 16 + c16;
        const float bias_v = bias[n];
#pragma unroll
        for (int r = 0; r < 4; ++r) {
            const int rr = rw + g * 4 + r;
            const unsigned short hv = f2bf(acc[nt][r] + bias_v);
            if (mat == 0)      Qb[(size_t)rr * H_ + n] = hv;
            else if (mat == 1) Kb[(size_t)rr * H_ + n] = hv;
            else {
                const int bb = rr >> 11, tt = rr & (T_ - 1);
                Vt[((size_t)bb * H_ + n) * T_ + tt] = hv;
            }
        }
    }
}

// ---------------------------------------------------------------------------
// stage one KV tile (K [32kv][256h] XOR-swz; V [256h][32kv] chunk-XOR-swz)
// ---------------------------------------------------------------------------
__device__ inline void stage_tile(const char* kbB, const char* vtB, int sk,
                                  unsigned short* Kdst, unsigned short* Vdst,
                                  int wid, int lane) {
#pragma unroll
    for (int j = 0; j < 8; ++j) {
        int off = wid * 8192 + j * 1024 + lane * 16;
        int row = off >> 9, colb = off & 511;
        glds16(kbB + (size_t)(sk + row) * 512 + (colb ^ ((row & 7) << 4)),
               (char*)Kdst + wid * 8192 + j * 1024);
    }
#pragma unroll
    for (int j = 0; j < 8; ++j) {
        int h = wid * 128 + j * 16 + (lane >> 2);
        int slot = lane & 3;
        int c = slot ^ ((h >> 1) & 3);   // logical kv-chunk stored at this slot
        glds16(vtB + (size_t)h * 4096 + (size_t)(sk + c * 8) * 2,
               (char*)Vdst + wid * 8192 + j * 1024);
    }
}

// ---------------------------------------------------------------------------
// Kernel 3: flash attention, swapped-operand (S^T / O^T) structure.
// Block = 2 waves x 16 q-rows = 32 q. KV tile = 32, dbuf. Grid 1024 1-D,
// long-first for backfill. Softmax fully per-lane (q = lane&15), 2 shfls.
// ---------------------------------------------------------------------------
__global__ __launch_bounds__(128) void attn(
    const unsigned short* __restrict__ Qb, const unsigned short* __restrict__ Kb,
    const unsigned short* __restrict__ Vt, float* __restrict__ out)
{
    const int r = blockIdx.x;                  // 0..1023
    const int qi = 63 - (r >> 4);              // long blocks dispatched first
    const int b = r & 15;
    const int q0 = qi * 32;
    const int ntiles = qi + 1;
    const int tid = threadIdx.x;
    const int wid = tid >> 6;
    const int lane = tid & 63;
    const int c16 = lane & 15;
    const int g = lane >> 4;
    const int qw = q0 + wid * 16;
    const int hsw = (c16 >> 1) & 3;            // chunk swizzle (V rows / P rows)

    __shared__ __align__(16) unsigned short Kl[2][KVB * 256];   // 2 x 16KB
    __shared__ __align__(16) unsigned short Vl[2][256 * KVB];   // 2 x 16KB
    __shared__ __align__(16) unsigned short Pl[2][16 * 32];     // 1KB/wave

    const char* kbB = (const char*)(Kb + (size_t)b * T_ * H_);
    const char* vtB = (const char*)(Vt + (size_t)b * H_ * T_);

    // Q fragments: B-operand of swapped QK^T (col=q at lane&15, k=h)
    short8 qf[8];
    const unsigned short* qp = Qb + (size_t)(b * T_ + qw + c16) * H_ + g * 8;
#pragma unroll
    for (int kc = 0; kc < 8; ++kc) qf[kc] = *(const short8*)(qp + kc * 32);

    f32x4 o[16];
#pragma unroll
    for (int i = 0; i < 16; ++i) o[i] = f32x4{0.f, 0.f, 0.f, 0.f};
    float m = -1e30f, ll = 0.f;
    const float inv_scale = 0.022097086912079608f;   // 1/sqrt(2048)
    const int qg = qw + c16;                          // this lane's q row

    stage_tile(kbB, vtB, 0, &Kl[0][0], &Vl[0][0], wid, lane);
    __syncthreads();

    for (int t = 0; t < ntiles; ++t) {
        const int cur = t & 1;
        const int sk = t * KVB;

        if (t + 1 < ntiles)
            stage_tile(kbB, vtB, sk + KVB, &Kl[cur ^ 1][0], &Vl[cur ^ 1][0], wid, lane);

        // ---- S^T = K Q^T : lane holds S[q=qg][kv = sk+ct*16+g*4+r] ----
        f32x4 sc[2];
#pragma unroll
        for (int ct = 0; ct < 2; ++ct) {
            f32x4 sa = f32x4{0.f, 0.f, 0.f, 0.f};
            const int row = ct * 16 + c16;
#pragma unroll
            for (int kc = 0; kc < 8; ++kc) {
                short8 kf = *(const short8*)((const char*)&Kl[cur][0] + row * 512 +
                                             ((kc * 64 + g * 16) ^ ((row & 7) << 4)));
                sa = __builtin_amdgcn_mfma_f32_16x16x32_bf16(kf, qf[kc], sa, 0, 0, 0);
            }
            sc[ct] = sa;
        }

        // ---- mask + scale ----
        const bool needm = (t == ntiles - 1);
        float p[8];
#pragma unroll
        for (int ct = 0; ct < 2; ++ct)
#pragma unroll
            for (int rr = 0; rr < 4; ++rr) {
                float v = sc[ct][rr] * inv_scale;
                if (needm && (sk + ct * 16 + g * 4 + rr) > qg) v = -1e30f;
                p[ct * 4 + rr] = v;
            }

        // ---- per-lane softmax (2 cross-lane ops) ----
        float pmax = fmaxf(fmaxf(fmaxf(p[0], p[1]), fmaxf(p[2], p[3])),
                           fmaxf(fmaxf(p[4], p[5]), fmaxf(p[6], p[7])));
        pmax = fmaxf(pmax, __shfl_xor(pmax, 16, 64));
        pmax = fmaxf(pmax, __shfl_xor(pmax, 32, 64));
        if (!__all(pmax <= m + 8.f)) {       // T13 defer-max
            const float nm = fmaxf(m, pmax);
            const float scf = __expf(m - nm);
            ll *= scf;
#pragma unroll
            for (int mt = 0; mt < 16; ++mt) {
                o[mt][0] *= scf; o[mt][1] *= scf;
                o[mt][2] *= scf; o[mt][3] *= scf;
            }
            m = nm;
        }
        float rsum = 0.f;
#pragma unroll
        for (int i = 0; i < 8; ++i) { p[i] = __expf(p[i] - m); rsum += p[i]; }
        rsum += __shfl_xor(rsum, 16, 64);
        rsum += __shfl_xor(rsum, 32, 64);
        ll += rsum;

        // ---- P -> bf16 -> wave-local swizzled LDS (4 b32 writes) ----
        unsigned int* pw = (unsigned int*)&Pl[wid][0];
#pragma unroll
        for (int ct = 0; ct < 2; ++ct)
#pragma unroll
            for (int pr = 0; pr < 2; ++pr) {
                int w = (ct * 8 + g * 2 + pr) ^ (hsw << 2);
                unsigned int v = (unsigned int)f2bf(p[ct * 4 + pr * 2]) |
                                 ((unsigned int)f2bf(p[ct * 4 + pr * 2 + 1]) << 16);
                pw[c16 * 16 + w] = v;
            }
        asm volatile("s_waitcnt lgkmcnt(0)" ::: "memory");
        __builtin_amdgcn_sched_barrier(0);
        short8 pb = *(const short8*)((const char*)&Pl[wid][0] + c16 * 64 +
                                     ((g ^ hsw) << 4));

        // ---- O^T += V^T P^T : o[mt][r] = O[q=qg][h=mt*16+g*4+r] ----
#pragma unroll
        for (int mt = 0; mt < 16; ++mt) {
            short8 vf = *(const short8*)((const char*)&Vl[cur][0] +
                                         (mt * 16 + c16) * 64 + ((g ^ hsw) << 4));
            o[mt] = __builtin_amdgcn_mfma_f32_16x16x32_bf16(vf, pb, o[mt], 0, 0, 0);
        }

        __syncthreads();   // drains prefetch glds; guards dbuf + Pl reuse
    }

    // ---- epilogue: coalesced f32x4 stores (16 rows x 64B per instr) ----
    const float inv = 1.f / ll;
    float* op = out + (size_t)(b * T_ + qg) * H_;
#pragma unroll
    for (int mt = 0; mt < 16; ++mt) {
        f32x4 vv;
        vv[0] = o[mt][0] * inv; vv[1] = o[mt][1] * inv;
        vv[2] = o[mt][2] * inv; vv[3] = o[mt][3] * inv;
        *(f32x4*)(op + mt * 16 + g * 4) = vv;
    }
}

// ---------------------------------------------------------------------------
extern "C" void kernel_launch(void* const* d_in, const int* in_sizes, int n_in,
                              void* d_out, int out_size, void* d_ws, size_t ws_size,
                              hipStream_t stream) {
    const float* x  = (const float*)d_in[0];
    const float* Wq = (const float*)d_in[1];
    const float* bq = (const float*)d_in[2];
    const float* Wk = (const float*)d_in[3];
    const float* bk = (const float*)d_in[4];
    const float* Wv = (const float*)d_in[5];
    const float* bv = (const float*)d_in[6];
    float* out = (float*)d_out;

    char* ws = (char*)d_ws;
    unsigned short* Wt = (unsigned short*)ws;                    // 1.5 MiB
    unsigned short* Qb = (unsigned short*)(ws + (2u  << 20));    // 16 MiB
    unsigned short* Kb = (unsigned short*)(ws + (18u << 20));    // 16 MiB
    unsigned short* Vt = (unsigned short*)(ws + (34u << 20));    // 16 MiB
    unsigned short* xb = (unsigned short*)(ws + (50u << 20));    // 64 MiB

    hipLaunchKernelGGL(xconv, dim3(2048), dim3(256), 0, stream, x, xb);
    hipLaunchKernelGGL(wconv, dim3((3 * C_ * H_ + 255) / 256), dim3(256), 0, stream,
                       Wq, Wk, Wv, Wt);
    hipLaunchKernelGGL(qkv_gemm, dim3(T_ * B_ / 128, 3), dim3(512), 0, stream,
                       xb, Wt, bq, bk, bv, Qb, Kb, Vt);
    hipLaunchKernelGGL(attn, dim3(1024), dim3(128), 0, stream,
                       Qb, Kb, Vt, out);
}